// Round 4
// baseline (862.179 us; speedup 1.0000x reference)
//
#include <hip/hip_runtime.h>

#define N_NODES 50000
#define N_EDGES 800000
#define NHID    256
#define NRES_P1 101

#define NB_SCAN  196          // ceil(50000/256)
#define NGRP     3125         // 50000 / 16 dst per block
#define POOL_GPB 392          // pool-agg blocks per slice (grid-stride)

typedef unsigned short u16;
typedef __attribute__((ext_vector_type(8))) short short8;   // 8 bf16
typedef __attribute__((ext_vector_type(4))) float f32x4;

static __device__ __forceinline__ u16 f2bf(float f) {       // RNE
    unsigned u = __float_as_uint(f);
    return (u16)((u + 0x7FFF + ((u >> 16) & 1)) >> 16);
}
static __device__ __forceinline__ float bflo(unsigned p) {
    return __uint_as_float(p << 16);
}
static __device__ __forceinline__ float bfhi(unsigned p) {
    return __uint_as_float(p & 0xffff0000u);
}

// ---------------------------------------------------------------- graph prep

__global__ void k_init(int* __restrict__ deg, int* __restrict__ indeg,
                       float* __restrict__ g) {
    int i = blockIdx.x * 256 + threadIdx.x;
    if (i < N_NODES) { deg[i] = 1; indeg[i] = 1; }   // self-loop pre-counted
    if (i < NHID) g[i] = 0.0f;                       // relu outputs >= 0
}

__global__ void k_count(const int* __restrict__ ei,
                        int* __restrict__ deg, int* __restrict__ indeg) {
    int e = blockIdx.x * 256 + threadIdx.x;
    if (e >= N_EDGES) return;
    int r = ei[e];            // row = source
    int c = ei[N_EDGES + e];  // col = destination
    if ((unsigned)r < N_NODES) atomicAdd(&deg[r], 1);
    if ((unsigned)c < N_NODES) atomicAdd(&indeg[c], 1);
}

// -------- 3-kernel exclusive scan of indeg -> rowptr (+cursor), dis fused

__global__ __launch_bounds__(256) void k_scan1(const int* __restrict__ cnt,
                                               int* __restrict__ bsum) {
    int t = threadIdx.x, lane = t & 63, wid = t >> 6;
    int i = blockIdx.x * 256 + t;
    int v = (i < N_NODES) ? cnt[i] : 0;
#pragma unroll
    for (int off = 32; off > 0; off >>= 1) v += __shfl_down(v, off, 64);
    __shared__ int ws[4];
    if (lane == 0) ws[wid] = v;
    __syncthreads();
    if (t == 0) bsum[blockIdx.x] = ws[0] + ws[1] + ws[2] + ws[3];
}

__global__ __launch_bounds__(256) void k_scan2(const int* __restrict__ bsum,
                                               int* __restrict__ bpre) {
    __shared__ int s[256];
    int t = threadIdx.x;
    int v0 = (t < NB_SCAN) ? bsum[t] : 0;
    s[t] = v0;
    __syncthreads();
    for (int off = 1; off < 256; off <<= 1) {
        int v = (t >= off) ? s[t - off] : 0;
        __syncthreads();
        s[t] += v;
        __syncthreads();
    }
    if (t < NB_SCAN) bpre[t] = s[t] - v0;   // exclusive
}

__global__ __launch_bounds__(256) void k_scan3(
    const int* __restrict__ cnt, const int* __restrict__ bpre,
    const int* __restrict__ deg, int* __restrict__ rowptr,
    int* __restrict__ cursor, float* __restrict__ dis) {
    int t = threadIdx.x, lane = t & 63, wid = t >> 6;
    int i = blockIdx.x * 256 + t;
    int v = (i < N_NODES) ? cnt[i] : 0;
    int sc = v;
#pragma unroll
    for (int off = 1; off < 64; off <<= 1) {
        int y = __shfl_up(sc, off, 64);
        if (lane >= off) sc += y;
    }
    __shared__ int wsum[4], wexcl[4];
    if (lane == 63) wsum[wid] = sc;
    __syncthreads();
    if (t == 0) {
        int r = 0;
#pragma unroll
        for (int w = 0; w < 4; ++w) { wexcl[w] = r; r += wsum[w]; }
    }
    __syncthreads();
    if (i < N_NODES) {
        int excl = bpre[blockIdx.x] + wexcl[wid] + sc - v;
        rowptr[i] = excl;
        cursor[i] = excl;
        dis[i] = rsqrtf((float)deg[i]);
    }
}

__global__ void k_fill(const int* __restrict__ ei,
                       int* __restrict__ cursor, int* __restrict__ srcl) {
    int e = blockIdx.x * 256 + threadIdx.x;
    if (e >= N_EDGES + N_NODES) return;
    int r, c;
    if (e < N_EDGES) { r = ei[e]; c = ei[N_EDGES + e]; }
    else             { r = c = e - N_EDGES; }            // self loops
    if ((unsigned)r >= N_NODES || (unsigned)c >= N_NODES) return;
    int pos = atomicAdd(&cursor[c], 1);
    srcl[pos] = r;
}

// ------------------------------------------------------------ bf16 prep

__global__ void k_cvtA(const float* __restrict__ x, const float* __restrict__ feat,
                       u16* __restrict__ A1) {
    int q = blockIdx.x * 256 + threadIdx.x;      // quad id
    if (q >= N_NODES * 64) return;
    int n = q >> 6, cq = (q & 63) << 2;
    float4 v = (cq < 128) ? *(const float4*)&x[n * 128 + cq]
                          : *(const float4*)&feat[n * 128 + cq - 128];
    uint2 p;
    p.x = (unsigned)f2bf(v.x) | ((unsigned)f2bf(v.y) << 16);
    p.y = (unsigned)f2bf(v.z) | ((unsigned)f2bf(v.w) << 16);
    *(uint2*)&A1[(size_t)n * 256 + cq] = p;
}

// WT[n][k] = bf16(W[k][n]),  W is [256][256] f32 row-major
__global__ void k_prep_w(const float* __restrict__ W, u16* __restrict__ WT) {
    int tid = blockIdx.x * 256 + threadIdx.x;    // 8192 threads
    if (tid >= 256 * 32) return;
    int n = tid >> 5, k8 = (tid & 31) << 3;
    u16 tmp[8];
#pragma unroll
    for (int i = 0; i < 8; ++i) tmp[i] = f2bf(W[(size_t)(k8 + i) * 256 + n]);
    *(uint4*)&WT[(size_t)n * 256 + k8] = *(uint4*)tmp;
}

// ------------------------------------------------------------- MFMA GEMM
// out[m][n] = bf16( dis[m] * ( sum_k A[m][k] * W[k][n] + bias[n] ) )

__global__ __launch_bounds__(256) void k_gemm_mfma(
    const u16* __restrict__ A, const u16* __restrict__ WT,
    const float* __restrict__ bias, const float* __restrict__ dis,
    u16* __restrict__ out, int M) {
    __shared__ u16 As[128][32];
    __shared__ u16 Bs[128][32];
    const int t = threadIdx.x;
    const int m0 = blockIdx.x * 128;
    const int n0 = blockIdx.y * 128;
    const int lane = t & 63;
    const int wave = t >> 6;
    const int wm = wave & 1, wn = wave >> 1;
    const int lr = lane & 15;   // fragment row (A) / col (B) / col (C)
    const int kg = lane >> 4;   // k-group of 8

    f32x4 acc[4][4] = {};

    for (int k0 = 0; k0 < 256; k0 += 32) {
#pragma unroll
        for (int i = 0; i < 2; ++i) {
            int idx = i * 256 + t;
            int row = idx >> 2;
            int kc = (idx & 3) << 3;
            int grow = m0 + row;
            uint4 va = {0u, 0u, 0u, 0u};
            if (grow < M) va = *(const uint4*)&A[(size_t)grow * 256 + k0 + kc];
            *(uint4*)&As[row][kc] = va;
            uint4 vb = *(const uint4*)&WT[(size_t)(n0 + row) * 256 + k0 + kc];
            *(uint4*)&Bs[row][kc] = vb;
        }
        __syncthreads();
        short8 af[4], bf[4];
#pragma unroll
        for (int mi = 0; mi < 4; ++mi)
            af[mi] = *(const short8*)&As[wm * 64 + mi * 16 + lr][kg * 8];
#pragma unroll
        for (int ni = 0; ni < 4; ++ni)
            bf[ni] = *(const short8*)&Bs[wn * 64 + ni * 16 + lr][kg * 8];
#pragma unroll
        for (int mi = 0; mi < 4; ++mi)
#pragma unroll
            for (int ni = 0; ni < 4; ++ni)
                acc[mi][ni] = __builtin_amdgcn_mfma_f32_16x16x32_bf16(
                    af[mi], bf[ni], acc[mi][ni], 0, 0, 0);
        __syncthreads();
    }

    const int orow = m0 + wm * 64;
    const int ocol = n0 + wn * 64;
#pragma unroll
    for (int mi = 0; mi < 4; ++mi) {
#pragma unroll
        for (int r = 0; r < 4; ++r) {
            int row = orow + mi * 16 + kg * 4 + r;
            if (row >= M) continue;
            float d = dis[row];
#pragma unroll
            for (int ni = 0; ni < 4; ++ni) {
                int col = ocol + ni * 16 + lr;
                float v = d * (acc[mi][ni][r] + bias[col]);
                out[(size_t)row * 256 + col] = f2bf(v);
            }
        }
    }
}

// ----------------------------------------------------------- CSR aggregation
// XCD-sliced: slice = blockIdx % 8 (round-robins onto the 8 XCDs); each slice
// owns 32 channels -> per-XCD gather working set 50000*64B = 3.2MB, L2-fits.
// Thread = (dst_local, chpair): 16 threads per dst, 4B (2 bf16) per gather.
// POOL variant keeps result in registers and max-reduces into g (fused pool).

template <bool POOL>
__global__ __launch_bounds__(256) void k_agg_sl(
    const int* __restrict__ rowptr, const int* __restrict__ rowend,
    const int* __restrict__ srcl, const u16* __restrict__ hs,
    const float* __restrict__ dis, u16* __restrict__ out,
    float* __restrict__ g) {
    const int t = threadIdx.x;
    const int lane = t & 63, wid = t >> 6;
    const int sl = blockIdx.x & 7;
    const int chpair = t & 15;
    const int dl = t >> 4;                     // dst_local 0..15
    const int ch = sl * 32 + (chpair << 1);

    if (!POOL) {
        int dst = (blockIdx.x >> 3) * 16 + dl;
        if (dst >= N_NODES) return;
        int s = rowptr[dst], e = rowend[dst];
        float a0 = 0.f, a1 = 0.f;
        for (int k = s; k < e; ++k) {
            int src = __builtin_nontemporal_load(&srcl[k]);
            unsigned v = *(const unsigned*)&hs[(size_t)src * 256 + ch];
            a0 += bflo(v); a1 += bfhi(v);
        }
        float d = dis[dst];
        a0 = fmaxf(a0 * d, 0.f); a1 = fmaxf(a1 * d, 0.f);
        unsigned p = (unsigned)f2bf(a0) | ((unsigned)f2bf(a1) << 16);
        *(unsigned*)&out[(size_t)dst * 256 + ch] = p;
    } else {
        float m0 = 0.f, m1 = 0.f;
        for (int gi = blockIdx.x >> 3; gi < NGRP; gi += POOL_GPB) {
            int dst = gi * 16 + dl;
            int s = rowptr[dst], e = rowend[dst];
            float a0 = 0.f, a1 = 0.f;
            for (int k = s; k < e; ++k) {
                int src = __builtin_nontemporal_load(&srcl[k]);
                unsigned v = *(const unsigned*)&hs[(size_t)src * 256 + ch];
                a0 += bflo(v); a1 += bfhi(v);
            }
            float d = dis[dst];
            m0 = fmaxf(m0, a0 * d);            // relu folded: m starts at 0
            m1 = fmaxf(m1, a1 * d);
        }
        // reduce max over the 16 dst_local within the wave (lanes ^16, ^32)
        m0 = fmaxf(m0, __shfl_xor(m0, 16, 64));
        m0 = fmaxf(m0, __shfl_xor(m0, 32, 64));
        m1 = fmaxf(m1, __shfl_xor(m1, 16, 64));
        m1 = fmaxf(m1, __shfl_xor(m1, 32, 64));
        __shared__ float lm[4][32];
        if (lane < 16) { lm[wid][lane * 2] = m0; lm[wid][lane * 2 + 1] = m1; }
        __syncthreads();
        if (t < 32) {
            float v = fmaxf(fmaxf(lm[0][t], lm[1][t]),
                            fmaxf(lm[2][t], lm[3][t]));
            atomicMax((int*)&g[sl * 32 + t], __float_as_int(v));
        }
    }
}

// --------------------------------------------------------------------- head

__global__ __launch_bounds__(128) void k_head(
    const float* __restrict__ g, const float* __restrict__ Wp,
    const float* __restrict__ bp, const float* __restrict__ Wq,
    const float* __restrict__ bq, float* __restrict__ out) {
    __shared__ float sg[NHID];
    __shared__ float red[128];
    int t = threadIdx.x;
    sg[t] = g[t];
    sg[t + 128] = g[t + 128];
    __syncthreads();

    float v = 0.0f;
    if (t < NRES_P1) {
        float acc = bp[t];
        for (int k = 0; k < NHID; ++k) acc = fmaf(sg[k], Wp[k * NRES_P1 + t], acc);
        out[t] = acc;
        v = acc;
    }
    red[t] = (t < NRES_P1) ? v : -1e30f;
    __syncthreads();
#pragma unroll
    for (int off = 64; off > 0; off >>= 1) {
        if (t < off) red[t] = fmaxf(red[t], red[t + off]);
        __syncthreads();
    }
    float mx = red[0];
    __syncthreads();
    float ex = (t < NRES_P1) ? expf(v - mx) : 0.0f;
    red[t] = ex;
    __syncthreads();
#pragma unroll
    for (int off = 64; off > 0; off >>= 1) {
        if (t < off) red[t] += red[t + off];
        __syncthreads();
    }
    float sum = red[0];
    if (t < NRES_P1) out[NRES_P1 + t] = ex / sum;

    if (t < 64) {
        float a = fmaf(sg[t], Wq[t], 0.f);
        a = fmaf(sg[t + 64],  Wq[t + 64],  a);
        a = fmaf(sg[t + 128], Wq[t + 128], a);
        a = fmaf(sg[t + 192], Wq[t + 192], a);
#pragma unroll
        for (int off = 32; off > 0; off >>= 1) a += __shfl_down(a, off, 64);
        if (t == 0) out[2 * NRES_P1] = a + bq[0];
    }
}

// -------------------------------------------------------------------- launch

static inline size_t align256(size_t x) { return (x + 255) & ~size_t(255); }

extern "C" void kernel_launch(void* const* d_in, const int* in_sizes, int n_in,
                              void* d_out, int out_size, void* d_ws,
                              size_t ws_size, hipStream_t stream) {
    (void)in_sizes; (void)n_in; (void)out_size; (void)ws_size;
    const float* x    = (const float*)d_in[0];
    const float* feat = (const float*)d_in[1];
    const int*   ei   = (const int*)d_in[2];   // int32 (harness-converted)
    const float* W1   = (const float*)d_in[3];
    const float* b1   = (const float*)d_in[4];
    const float* W2   = (const float*)d_in[5];
    const float* b2   = (const float*)d_in[6];
    const float* Wp   = (const float*)d_in[7];
    const float* bp   = (const float*)d_in[8];
    const float* Wq   = (const float*)d_in[9];
    const float* bq   = (const float*)d_in[10];
    float* out = (float*)d_out;

    char* ws = (char*)d_ws;
    size_t off = 0;
    auto alloc = [&](size_t bytes) {
        void* p = ws + off;
        off = align256(off + bytes);
        return p;
    };
    int*   deg    = (int*)alloc(4ull * N_NODES);
    int*   indeg  = (int*)alloc(4ull * N_NODES);
    int*   rowptr = (int*)alloc(4ull * (N_NODES + 1));
    int*   cursor = (int*)alloc(4ull * (N_NODES + 1));
    int*   srcl   = (int*)alloc(4ull * (N_EDGES + N_NODES));
    int*   bsum   = (int*)alloc(4ull * NB_SCAN);
    int*   bpre   = (int*)alloc(4ull * NB_SCAN);
    float* dis    = (float*)alloc(4ull * N_NODES);
    float* g      = (float*)alloc(4ull * NHID);
    u16*   W1T    = (u16*)alloc(2ull * 256 * 256);
    u16*   W2T    = (u16*)alloc(2ull * 256 * 256);
    u16*   bufA16 = (u16*)alloc(2ull * N_NODES * 256);   // A1, later h3
    u16*   buf1   = (u16*)alloc(2ull * N_NODES * 256);   // h1
    u16*   buf2   = (u16*)alloc(2ull * N_NODES * 256);   // h2

    const int nb_nodes = (N_NODES + 255) / 256;

    k_init<<<nb_nodes, 256, 0, stream>>>(deg, indeg, g);
    k_count<<<(N_EDGES + 255) / 256, 256, 0, stream>>>(ei, deg, indeg);
    k_scan1<<<NB_SCAN, 256, 0, stream>>>(indeg, bsum);
    k_scan2<<<1, 256, 0, stream>>>(bsum, bpre);
    k_scan3<<<NB_SCAN, 256, 0, stream>>>(indeg, bpre, deg, rowptr, cursor, dis);
    k_fill<<<(N_EDGES + N_NODES + 255) / 256, 256, 0, stream>>>(ei, cursor, srcl);

    k_cvtA<<<(N_NODES * 64 + 255) / 256, 256, 0, stream>>>(x, feat, bufA16);
    k_prep_w<<<32, 256, 0, stream>>>(W1, W1T);
    k_prep_w<<<32, 256, 0, stream>>>(W2, W2T);

    dim3 ggrid((N_NODES + 127) / 128, 2);
    // conv1 linear: h1 = bf16(dis .* (A1 @ W1 + b1))
    k_gemm_mfma<<<ggrid, 256, 0, stream>>>(bufA16, W1T, b1, dis, buf1, N_NODES);
    // agg1: h2 = bf16(relu(dis .* gather-sum(h1)))   (XCD-sliced)
    k_agg_sl<false><<<NGRP * 8, 256, 0, stream>>>(rowptr, cursor, srcl,
                                                  buf1, dis, buf2, nullptr);
    // conv2 linear: h3 = bf16(dis .* (h2 @ W2 + b2))
    k_gemm_mfma<<<ggrid, 256, 0, stream>>>(buf2, W2T, b2, dis, bufA16, N_NODES);
    // agg2 + fused global max pool -> g
    k_agg_sl<true><<<POOL_GPB * 8, 256, 0, stream>>>(rowptr, cursor, srcl,
                                                     bufA16, dis, nullptr, g);

    k_head<<<1, 128, 0, stream>>>(g, Wp, bp, Wq, bq, out);
}

// Round 5
// 358.963 us; speedup vs baseline: 2.4019x; 2.4019x over previous
//
#include <hip/hip_runtime.h>

#define N_NODES 50000
#define N_EDGES 800000
#define NHID    256
#define NRES_P1 101

#define NB_SCAN     196        // ceil(50000/256)
#define POOL_BLOCKS 1024       // fused agg2+pool grid

typedef unsigned short u16;
typedef __attribute__((ext_vector_type(8))) short short8;   // 8 bf16
typedef __attribute__((ext_vector_type(4))) float f32x4;

static __device__ __forceinline__ u16 f2bf(float f) {       // RNE
    unsigned u = __float_as_uint(f);
    return (u16)((u + 0x7FFF + ((u >> 16) & 1)) >> 16);
}
static __device__ __forceinline__ float bflo(unsigned p) {
    return __uint_as_float(p << 16);
}
static __device__ __forceinline__ float bfhi(unsigned p) {
    return __uint_as_float(p & 0xffff0000u);
}

// ---------------------------------------------------------------- graph prep

__global__ void k_init(int* __restrict__ deg, int* __restrict__ indeg,
                       float* __restrict__ g) {
    int i = blockIdx.x * 256 + threadIdx.x;
    if (i < N_NODES) { deg[i] = 1; indeg[i] = 1; }   // self-loop pre-counted
    if (i < NHID) g[i] = 0.0f;                       // relu outputs >= 0
}

__global__ void k_count(const int* __restrict__ ei,
                        int* __restrict__ deg, int* __restrict__ indeg) {
    int e = blockIdx.x * 256 + threadIdx.x;
    if (e >= N_EDGES) return;
    int r = ei[e];            // row = source
    int c = ei[N_EDGES + e];  // col = destination
    if ((unsigned)r < N_NODES) atomicAdd(&deg[r], 1);
    if ((unsigned)c < N_NODES) atomicAdd(&indeg[c], 1);
}

// -------- 3-kernel exclusive scan of indeg -> rowptr (+cursor), dis fused

__global__ __launch_bounds__(256) void k_scan1(const int* __restrict__ cnt,
                                               int* __restrict__ bsum) {
    int t = threadIdx.x, lane = t & 63, wid = t >> 6;
    int i = blockIdx.x * 256 + t;
    int v = (i < N_NODES) ? cnt[i] : 0;
#pragma unroll
    for (int off = 32; off > 0; off >>= 1) v += __shfl_down(v, off, 64);
    __shared__ int ws[4];
    if (lane == 0) ws[wid] = v;
    __syncthreads();
    if (t == 0) bsum[blockIdx.x] = ws[0] + ws[1] + ws[2] + ws[3];
}

__global__ __launch_bounds__(256) void k_scan2(const int* __restrict__ bsum,
                                               int* __restrict__ bpre) {
    __shared__ int s[256];
    int t = threadIdx.x;
    int v0 = (t < NB_SCAN) ? bsum[t] : 0;
    s[t] = v0;
    __syncthreads();
    for (int off = 1; off < 256; off <<= 1) {
        int v = (t >= off) ? s[t - off] : 0;
        __syncthreads();
        s[t] += v;
        __syncthreads();
    }
    if (t < NB_SCAN) bpre[t] = s[t] - v0;   // exclusive
}

__global__ __launch_bounds__(256) void k_scan3(
    const int* __restrict__ cnt, const int* __restrict__ bpre,
    const int* __restrict__ deg, int* __restrict__ rowptr,
    int* __restrict__ cursor, float* __restrict__ dis) {
    int t = threadIdx.x, lane = t & 63, wid = t >> 6;
    int i = blockIdx.x * 256 + t;
    int v = (i < N_NODES) ? cnt[i] : 0;
    int sc = v;
#pragma unroll
    for (int off = 1; off < 64; off <<= 1) {
        int y = __shfl_up(sc, off, 64);
        if (lane >= off) sc += y;
    }
    __shared__ int wsum[4], wexcl[4];
    if (lane == 63) wsum[wid] = sc;
    __syncthreads();
    if (t == 0) {
        int r = 0;
#pragma unroll
        for (int w = 0; w < 4; ++w) { wexcl[w] = r; r += wsum[w]; }
    }
    __syncthreads();
    if (i < N_NODES) {
        int excl = bpre[blockIdx.x] + wexcl[wid] + sc - v;
        rowptr[i] = excl;
        cursor[i] = excl;
        dis[i] = rsqrtf((float)deg[i]);
    }
}

__global__ void k_fill(const int* __restrict__ ei,
                       int* __restrict__ cursor, int* __restrict__ srcl) {
    int e = blockIdx.x * 256 + threadIdx.x;
    if (e >= N_EDGES + N_NODES) return;
    int r, c;
    if (e < N_EDGES) { r = ei[e]; c = ei[N_EDGES + e]; }
    else             { r = c = e - N_EDGES; }            // self loops
    if ((unsigned)r >= N_NODES || (unsigned)c >= N_NODES) return;
    int pos = atomicAdd(&cursor[c], 1);
    srcl[pos] = r;
}

// ------------------------------------------------------------ bf16 prep

__global__ void k_cvtA(const float* __restrict__ x, const float* __restrict__ feat,
                       u16* __restrict__ A1) {
    int q = blockIdx.x * 256 + threadIdx.x;      // quad id
    if (q >= N_NODES * 64) return;
    int n = q >> 6, cq = (q & 63) << 2;
    float4 v = (cq < 128) ? *(const float4*)&x[n * 128 + cq]
                          : *(const float4*)&feat[n * 128 + cq - 128];
    uint2 p;
    p.x = (unsigned)f2bf(v.x) | ((unsigned)f2bf(v.y) << 16);
    p.y = (unsigned)f2bf(v.z) | ((unsigned)f2bf(v.w) << 16);
    *(uint2*)&A1[(size_t)n * 256 + cq] = p;
}

// WT[n][k] = bf16(W[k][n]),  W is [256][256] f32 row-major
__global__ void k_prep_w(const float* __restrict__ W, u16* __restrict__ WT) {
    int tid = blockIdx.x * 256 + threadIdx.x;    // 8192 threads
    if (tid >= 256 * 32) return;
    int n = tid >> 5, k8 = (tid & 31) << 3;
    u16 tmp[8];
#pragma unroll
    for (int i = 0; i < 8; ++i) tmp[i] = f2bf(W[(size_t)(k8 + i) * 256 + n]);
    *(uint4*)&WT[(size_t)n * 256 + k8] = *(uint4*)tmp;
}

// ------------------------------------------------------------- MFMA GEMM
// out[m][n] = bf16( dis[m] * ( sum_k A[m][k] * W[k][n] + bias[n] ) )

__global__ __launch_bounds__(256) void k_gemm_mfma(
    const u16* __restrict__ A, const u16* __restrict__ WT,
    const float* __restrict__ bias, const float* __restrict__ dis,
    u16* __restrict__ out, int M) {
    __shared__ u16 As[128][32];
    __shared__ u16 Bs[128][32];
    const int t = threadIdx.x;
    const int m0 = blockIdx.x * 128;
    const int n0 = blockIdx.y * 128;
    const int lane = t & 63;
    const int wave = t >> 6;
    const int wm = wave & 1, wn = wave >> 1;
    const int lr = lane & 15;   // fragment row (A) / col (B) / col (C)
    const int kg = lane >> 4;   // k-group of 8

    f32x4 acc[4][4] = {};

    for (int k0 = 0; k0 < 256; k0 += 32) {
#pragma unroll
        for (int i = 0; i < 2; ++i) {
            int idx = i * 256 + t;
            int row = idx >> 2;
            int kc = (idx & 3) << 3;
            int grow = m0 + row;
            uint4 va = {0u, 0u, 0u, 0u};
            if (grow < M) va = *(const uint4*)&A[(size_t)grow * 256 + k0 + kc];
            *(uint4*)&As[row][kc] = va;
            uint4 vb = *(const uint4*)&WT[(size_t)(n0 + row) * 256 + k0 + kc];
            *(uint4*)&Bs[row][kc] = vb;
        }
        __syncthreads();
        short8 af[4], bf[4];
#pragma unroll
        for (int mi = 0; mi < 4; ++mi)
            af[mi] = *(const short8*)&As[wm * 64 + mi * 16 + lr][kg * 8];
#pragma unroll
        for (int ni = 0; ni < 4; ++ni)
            bf[ni] = *(const short8*)&Bs[wn * 64 + ni * 16 + lr][kg * 8];
#pragma unroll
        for (int mi = 0; mi < 4; ++mi)
#pragma unroll
            for (int ni = 0; ni < 4; ++ni)
                acc[mi][ni] = __builtin_amdgcn_mfma_f32_16x16x32_bf16(
                    af[mi], bf[ni], acc[mi][ni], 0, 0, 0);
        __syncthreads();
    }

    const int orow = m0 + wm * 64;
    const int ocol = n0 + wn * 64;
#pragma unroll
    for (int mi = 0; mi < 4; ++mi) {
#pragma unroll
        for (int r = 0; r < 4; ++r) {
            int row = orow + mi * 16 + kg * 4 + r;
            if (row >= M) continue;
            float d = dis[row];
#pragma unroll
            for (int ni = 0; ni < 4; ++ni) {
                int col = ocol + ni * 16 + lr;
                float v = d * (acc[mi][ni][r] + bias[col]);
                out[(size_t)row * 256 + col] = f2bf(v);
            }
        }
    }
}

// ----------------------------------------------------------- CSR aggregation
// Wave per dst (R3 structure — proven); lane owns 4 channels (uint2 = 8B).
// Edge loop unrolled x4 with batched srcl loads -> 4 gathers in flight.

static __device__ __forceinline__ void gather_row(
    const int* __restrict__ srcl, int s, int e, const u16* __restrict__ base,
    float& a0, float& a1, float& a2, float& a3) {
    int k = s;
    for (; k + 4 <= e; k += 4) {
        int i0 = srcl[k], i1 = srcl[k + 1], i2 = srcl[k + 2], i3 = srcl[k + 3];
        uint2 v0 = *(const uint2*)(base + (size_t)i0 * 256);
        uint2 v1 = *(const uint2*)(base + (size_t)i1 * 256);
        uint2 v2 = *(const uint2*)(base + (size_t)i2 * 256);
        uint2 v3 = *(const uint2*)(base + (size_t)i3 * 256);
        a0 += bflo(v0.x); a1 += bfhi(v0.x); a2 += bflo(v0.y); a3 += bfhi(v0.y);
        a0 += bflo(v1.x); a1 += bfhi(v1.x); a2 += bflo(v1.y); a3 += bfhi(v1.y);
        a0 += bflo(v2.x); a1 += bfhi(v2.x); a2 += bflo(v2.y); a3 += bfhi(v2.y);
        a0 += bflo(v3.x); a1 += bfhi(v3.x); a2 += bflo(v3.y); a3 += bfhi(v3.y);
    }
    for (; k < e; ++k) {
        int i0 = srcl[k];
        uint2 v = *(const uint2*)(base + (size_t)i0 * 256);
        a0 += bflo(v.x); a1 += bfhi(v.x); a2 += bflo(v.y); a3 += bfhi(v.y);
    }
}

__global__ __launch_bounds__(256) void k_agg(
    const int* __restrict__ rowptr, const int* __restrict__ rowend,
    const int* __restrict__ srcl, const u16* __restrict__ hs,
    const float* __restrict__ dis, u16* __restrict__ out) {
    int wave = threadIdx.x >> 6;
    int lane = threadIdx.x & 63;
    int dst = blockIdx.x * 4 + wave;
    if (dst >= N_NODES) return;
    int s = rowptr[dst], e = rowend[dst];
    int ch = lane << 2;
    float a0 = 0.f, a1 = 0.f, a2 = 0.f, a3 = 0.f;
    gather_row(srcl, s, e, hs + ch, a0, a1, a2, a3);
    float d = dis[dst];
    a0 = fmaxf(a0 * d, 0.f); a1 = fmaxf(a1 * d, 0.f);
    a2 = fmaxf(a2 * d, 0.f); a3 = fmaxf(a3 * d, 0.f);
    uint2 p;
    p.x = (unsigned)f2bf(a0) | ((unsigned)f2bf(a1) << 16);
    p.y = (unsigned)f2bf(a2) | ((unsigned)f2bf(a3) << 16);
    *(uint2*)&out[(size_t)dst * 256 + ch] = p;
}

// agg2 + global max pool fused: grid-stride waves, per-block LDS max,
// one atomicMax per channel per block (g pre-zeroed; all values >= 0).

__global__ __launch_bounds__(256) void k_agg_pool(
    const int* __restrict__ rowptr, const int* __restrict__ rowend,
    const int* __restrict__ srcl, const u16* __restrict__ hs,
    const float* __restrict__ dis, float* __restrict__ g) {
    int wave = threadIdx.x >> 6;
    int lane = threadIdx.x & 63;
    int ch = lane << 2;
    const u16* base = hs + ch;
    float m0 = 0.f, m1 = 0.f, m2 = 0.f, m3 = 0.f;   // relu folded (max >= 0)
    for (int dst = blockIdx.x * 4 + wave; dst < N_NODES;
         dst += POOL_BLOCKS * 4) {
        int s = rowptr[dst], e = rowend[dst];
        float a0 = 0.f, a1 = 0.f, a2 = 0.f, a3 = 0.f;
        gather_row(srcl, s, e, base, a0, a1, a2, a3);
        float d = dis[dst];
        m0 = fmaxf(m0, a0 * d); m1 = fmaxf(m1, a1 * d);
        m2 = fmaxf(m2, a2 * d); m3 = fmaxf(m3, a3 * d);
    }
    __shared__ float lm[4][256];
    lm[wave][ch] = m0; lm[wave][ch + 1] = m1;
    lm[wave][ch + 2] = m2; lm[wave][ch + 3] = m3;
    __syncthreads();
    int t = threadIdx.x;
    float v = fmaxf(fmaxf(lm[0][t], lm[1][t]), fmaxf(lm[2][t], lm[3][t]));
    atomicMax((int*)&g[t], __float_as_int(v));
}

// --------------------------------------------------------------------- head

__global__ __launch_bounds__(128) void k_head(
    const float* __restrict__ g, const float* __restrict__ Wp,
    const float* __restrict__ bp, const float* __restrict__ Wq,
    const float* __restrict__ bq, float* __restrict__ out) {
    __shared__ float sg[NHID];
    __shared__ float red[128];
    int t = threadIdx.x;
    sg[t] = g[t];
    sg[t + 128] = g[t + 128];
    __syncthreads();

    float v = 0.0f;
    if (t < NRES_P1) {
        float acc = bp[t];
        for (int k = 0; k < NHID; ++k) acc = fmaf(sg[k], Wp[k * NRES_P1 + t], acc);
        out[t] = acc;
        v = acc;
    }
    red[t] = (t < NRES_P1) ? v : -1e30f;
    __syncthreads();
#pragma unroll
    for (int off = 64; off > 0; off >>= 1) {
        if (t < off) red[t] = fmaxf(red[t], red[t + off]);
        __syncthreads();
    }
    float mx = red[0];
    __syncthreads();
    float ex = (t < NRES_P1) ? expf(v - mx) : 0.0f;
    red[t] = ex;
    __syncthreads();
#pragma unroll
    for (int off = 64; off > 0; off >>= 1) {
        if (t < off) red[t] += red[t + off];
        __syncthreads();
    }
    float sum = red[0];
    if (t < NRES_P1) out[NRES_P1 + t] = ex / sum;

    if (t < 64) {
        float a = fmaf(sg[t], Wq[t], 0.f);
        a = fmaf(sg[t + 64],  Wq[t + 64],  a);
        a = fmaf(sg[t + 128], Wq[t + 128], a);
        a = fmaf(sg[t + 192], Wq[t + 192], a);
#pragma unroll
        for (int off = 32; off > 0; off >>= 1) a += __shfl_down(a, off, 64);
        if (t == 0) out[2 * NRES_P1] = a + bq[0];
    }
}

// -------------------------------------------------------------------- launch

static inline size_t align256(size_t x) { return (x + 255) & ~size_t(255); }

extern "C" void kernel_launch(void* const* d_in, const int* in_sizes, int n_in,
                              void* d_out, int out_size, void* d_ws,
                              size_t ws_size, hipStream_t stream) {
    (void)in_sizes; (void)n_in; (void)out_size; (void)ws_size;
    const float* x    = (const float*)d_in[0];
    const float* feat = (const float*)d_in[1];
    const int*   ei   = (const int*)d_in[2];   // int32 (harness-converted)
    const float* W1   = (const float*)d_in[3];
    const float* b1   = (const float*)d_in[4];
    const float* W2   = (const float*)d_in[5];
    const float* b2   = (const float*)d_in[6];
    const float* Wp   = (const float*)d_in[7];
    const float* bp   = (const float*)d_in[8];
    const float* Wq   = (const float*)d_in[9];
    const float* bq   = (const float*)d_in[10];
    float* out = (float*)d_out;

    char* ws = (char*)d_ws;
    size_t off = 0;
    auto alloc = [&](size_t bytes) {
        void* p = ws + off;
        off = align256(off + bytes);
        return p;
    };
    int*   deg    = (int*)alloc(4ull * N_NODES);
    int*   indeg  = (int*)alloc(4ull * N_NODES);
    int*   rowptr = (int*)alloc(4ull * (N_NODES + 1));
    int*   cursor = (int*)alloc(4ull * (N_NODES + 1));
    int*   srcl   = (int*)alloc(4ull * (N_EDGES + N_NODES));
    int*   bsum   = (int*)alloc(4ull * NB_SCAN);
    int*   bpre   = (int*)alloc(4ull * NB_SCAN);
    float* dis    = (float*)alloc(4ull * N_NODES);
    float* g      = (float*)alloc(4ull * NHID);
    u16*   W1T    = (u16*)alloc(2ull * 256 * 256);
    u16*   W2T    = (u16*)alloc(2ull * 256 * 256);
    u16*   bufA16 = (u16*)alloc(2ull * N_NODES * 256);   // A1, later h3
    u16*   buf1   = (u16*)alloc(2ull * N_NODES * 256);   // h1
    u16*   buf2   = (u16*)alloc(2ull * N_NODES * 256);   // h2

    const int nb_nodes = (N_NODES + 255) / 256;

    k_init<<<nb_nodes, 256, 0, stream>>>(deg, indeg, g);
    k_count<<<(N_EDGES + 255) / 256, 256, 0, stream>>>(ei, deg, indeg);
    k_scan1<<<NB_SCAN, 256, 0, stream>>>(indeg, bsum);
    k_scan2<<<1, 256, 0, stream>>>(bsum, bpre);
    k_scan3<<<NB_SCAN, 256, 0, stream>>>(indeg, bpre, deg, rowptr, cursor, dis);
    k_fill<<<(N_EDGES + N_NODES + 255) / 256, 256, 0, stream>>>(ei, cursor, srcl);

    k_cvtA<<<(N_NODES * 64 + 255) / 256, 256, 0, stream>>>(x, feat, bufA16);
    k_prep_w<<<32, 256, 0, stream>>>(W1, W1T);
    k_prep_w<<<32, 256, 0, stream>>>(W2, W2T);

    dim3 ggrid((N_NODES + 127) / 128, 2);
    // conv1 linear: h1 = bf16(dis .* (A1 @ W1 + b1))
    k_gemm_mfma<<<ggrid, 256, 0, stream>>>(bufA16, W1T, b1, dis, buf1, N_NODES);
    // agg1: h2 = bf16(relu(dis .* gather-sum(h1)))
    k_agg<<<(N_NODES + 3) / 4, 256, 0, stream>>>(rowptr, cursor, srcl,
                                                 buf1, dis, buf2);
    // conv2 linear: h3 = bf16(dis .* (h2 @ W2 + b2))
    k_gemm_mfma<<<ggrid, 256, 0, stream>>>(buf2, W2T, b2, dis, bufA16, N_NODES);
    // agg2 + fused global max pool -> g
    k_agg_pool<<<POOL_BLOCKS, 256, 0, stream>>>(rowptr, cursor, srcl,
                                                bufA16, dis, g);

    k_head<<<1, 128, 0, stream>>>(g, Wp, bp, Wq, bq, out);
}

// Round 6
// 346.681 us; speedup vs baseline: 2.4869x; 1.0354x over previous
//
#include <hip/hip_runtime.h>

#define N_NODES 50000
#define N_EDGES 800000
#define NHID    256
#define NRES_P1 101

#define NB_SCAN     196        // ceil(50000/256)
#define POOL_BLOCKS 2048       // fused agg2+pool grid
#define LDK         40         // LDS k-stride (u16): 80B, 16B-aligned, 2-way banks

typedef unsigned short u16;
typedef __attribute__((ext_vector_type(8))) short short8;   // 8 bf16
typedef __attribute__((ext_vector_type(4))) float f32x4;

static __device__ __forceinline__ unsigned f2bf(float f) {  // RNE -> low 16
    unsigned u = __float_as_uint(f);
    return (u + 0x7FFF + ((u >> 16) & 1)) >> 16;
}
static __device__ __forceinline__ float bflo(unsigned p) {
    return __uint_as_float(p << 16);
}
static __device__ __forceinline__ float bfhi(unsigned p) {
    return __uint_as_float(p & 0xffff0000u);
}

// ---------------------------------------------------------------- graph prep

__global__ void k_count(const int* __restrict__ ei,
                        int* __restrict__ deg, int* __restrict__ indeg) {
    int tid = blockIdx.x * 256 + threadIdx.x;
    if (tid >= N_EDGES / 4) return;
    int4 r = *(const int4*)&ei[tid * 4];
    int4 c = *(const int4*)&ei[N_EDGES + tid * 4];
    atomicAdd(&deg[r.x], 1); atomicAdd(&deg[r.y], 1);
    atomicAdd(&deg[r.z], 1); atomicAdd(&deg[r.w], 1);
    atomicAdd(&indeg[c.x], 1); atomicAdd(&indeg[c.y], 1);
    atomicAdd(&indeg[c.z], 1); atomicAdd(&indeg[c.w], 1);
}

// 3-kernel exclusive scan of (indeg+1) -> rowptr (+cursor); dis fused in scan3

__global__ __launch_bounds__(256) void k_scan1(const int* __restrict__ cnt,
                                               int* __restrict__ bsum) {
    int t = threadIdx.x, lane = t & 63, wid = t >> 6;
    int i = blockIdx.x * 256 + t;
    int v = (i < N_NODES) ? cnt[i] + 1 : 0;      // +1 = self-loop
#pragma unroll
    for (int off = 32; off > 0; off >>= 1) v += __shfl_down(v, off, 64);
    __shared__ int ws[4];
    if (lane == 0) ws[wid] = v;
    __syncthreads();
    if (t == 0) bsum[blockIdx.x] = ws[0] + ws[1] + ws[2] + ws[3];
}

__global__ __launch_bounds__(256) void k_scan2(const int* __restrict__ bsum,
                                               int* __restrict__ bpre) {
    __shared__ int s[256];
    int t = threadIdx.x;
    int v0 = (t < NB_SCAN) ? bsum[t] : 0;
    s[t] = v0;
    __syncthreads();
    for (int off = 1; off < 256; off <<= 1) {
        int v = (t >= off) ? s[t - off] : 0;
        __syncthreads();
        s[t] += v;
        __syncthreads();
    }
    if (t < NB_SCAN) bpre[t] = s[t] - v0;   // exclusive
}

__global__ __launch_bounds__(256) void k_scan3(
    const int* __restrict__ cnt, const int* __restrict__ bpre,
    const int* __restrict__ deg, int* __restrict__ rowptr,
    int* __restrict__ cursor, float* __restrict__ dis) {
    int t = threadIdx.x, lane = t & 63, wid = t >> 6;
    int i = blockIdx.x * 256 + t;
    int v = (i < N_NODES) ? cnt[i] + 1 : 0;
    int sc = v;
#pragma unroll
    for (int off = 1; off < 64; off <<= 1) {
        int y = __shfl_up(sc, off, 64);
        if (lane >= off) sc += y;
    }
    __shared__ int wsum[4], wexcl[4];
    if (lane == 63) wsum[wid] = sc;
    __syncthreads();
    if (t == 0) {
        int r = 0;
#pragma unroll
        for (int w = 0; w < 4; ++w) { wexcl[w] = r; r += wsum[w]; }
    }
    __syncthreads();
    if (i < N_NODES) {
        int excl = bpre[blockIdx.x] + wexcl[wid] + sc - v;
        rowptr[i] = excl;
        cursor[i] = excl;
        dis[i] = rsqrtf((float)(deg[i] + 1));
    }
}

__global__ void k_fill(const int* __restrict__ ei,
                       int* __restrict__ cursor, int* __restrict__ srcl) {
    int tid = blockIdx.x * 256 + threadIdx.x;
    if (tid < N_EDGES / 4) {
        int4 r = *(const int4*)&ei[tid * 4];
        int4 c = *(const int4*)&ei[N_EDGES + tid * 4];
        int p;
        p = atomicAdd(&cursor[c.x], 1); srcl[p] = r.x;
        p = atomicAdd(&cursor[c.y], 1); srcl[p] = r.y;
        p = atomicAdd(&cursor[c.z], 1); srcl[p] = r.z;
        p = atomicAdd(&cursor[c.w], 1); srcl[p] = r.w;
    } else if (tid < N_EDGES / 4 + N_NODES / 4) {
        int n4 = (tid - N_EDGES / 4) * 4;
#pragma unroll
        for (int j = 0; j < 4; ++j) {
            int n = n4 + j;
            int p = atomicAdd(&cursor[n], 1);
            srcl[p] = n;                        // self loop
        }
    }
}

// both weight transposes in one dispatch: WT[n][k] = bf16(W[k][n])
__global__ void k_prep_w2(const float* __restrict__ W1, const float* __restrict__ W2,
                          u16* __restrict__ W1T, u16* __restrict__ W2T) {
    int tid = blockIdx.x * 256 + threadIdx.x;    // 16384
    const float* W = (tid < 8192) ? W1 : W2;
    u16* WT = (tid < 8192) ? W1T : W2T;
    int id = tid & 8191;
    int n = id >> 5, k8 = (id & 31) << 3;
    u16 tmp[8];
#pragma unroll
    for (int i = 0; i < 8; ++i) tmp[i] = (u16)f2bf(W[(size_t)(k8 + i) * 256 + n]);
    *(uint4*)&WT[(size_t)n * 256 + k8] = *(uint4*)tmp;
}

// ------------------------------------------------------------- MFMA GEMM
// out[m][n] = bf16( dis[m] * ( sum_k A[m][k] * W[k][n] + bias[n] ) )
// BM=128, BN=256 (full N, single pass over A), BK=32, 256 thr = 2x2 waves,
// wave-tile 64x128 (acc 4x8 frags). SPLIT: A = concat(x,feat) f32, converted
// to bf16 during staging (fused cvtA).

template <bool SPLIT>
__global__ __launch_bounds__(256, 2) void k_gemm_mfma(
    const void* __restrict__ A0v, const float* __restrict__ A1,
    const u16* __restrict__ WT, const float* __restrict__ bias,
    const float* __restrict__ dis, u16* __restrict__ out, int M) {
    __shared__ u16 As[128][LDK];
    __shared__ u16 Bs[256][LDK];
    const int t = threadIdx.x;
    const int m0 = blockIdx.x * 128;
    const int lane = t & 63, wave = t >> 6;
    const int wm = wave & 1, wn = wave >> 1;
    const int lr = lane & 15, kg = lane >> 4;

    f32x4 acc[4][8] = {};

    for (int k0 = 0; k0 < 256; k0 += 32) {
        // A tile: 128 rows x 32 k = 512 chunks of 8 bf16; 2 per thread
#pragma unroll
        for (int i = 0; i < 2; ++i) {
            int idx = i * 256 + t;
            int row = idx >> 2, kc = (idx & 3) << 3;
            int grow = m0 + row;
            uint4 pk = {0u, 0u, 0u, 0u};
            if (grow < M) {
                if (SPLIT) {
                    int k = k0 + kc;            // 8-aligned, never straddles 128
                    const float* src = (k < 128)
                        ? ((const float*)A0v + (size_t)grow * 128 + k)
                        : (A1 + (size_t)grow * 128 + (k - 128));
                    float4 f0 = *(const float4*)src;
                    float4 f1 = *(const float4*)(src + 4);
                    pk.x = f2bf(f0.x) | (f2bf(f0.y) << 16);
                    pk.y = f2bf(f0.z) | (f2bf(f0.w) << 16);
                    pk.z = f2bf(f1.x) | (f2bf(f1.y) << 16);
                    pk.w = f2bf(f1.z) | (f2bf(f1.w) << 16);
                } else {
                    pk = *(const uint4*)((const u16*)A0v +
                                         (size_t)grow * 256 + k0 + kc);
                }
            }
            *(uint4*)&As[row][kc] = pk;
        }
        // B tile: 256 n-rows x 32 k = 1024 chunks; 4 per thread
#pragma unroll
        for (int i = 0; i < 4; ++i) {
            int idx = i * 256 + t;
            int n = idx >> 2, kc = (idx & 3) << 3;
            *(uint4*)&Bs[n][kc] = *(const uint4*)&WT[(size_t)n * 256 + k0 + kc];
        }
        __syncthreads();
        short8 af[4], bf[8];
#pragma unroll
        for (int mi = 0; mi < 4; ++mi)
            af[mi] = *(const short8*)&As[wm * 64 + mi * 16 + lr][kg * 8];
#pragma unroll
        for (int ni = 0; ni < 8; ++ni)
            bf[ni] = *(const short8*)&Bs[wn * 128 + ni * 16 + lr][kg * 8];
#pragma unroll
        for (int mi = 0; mi < 4; ++mi)
#pragma unroll
            for (int ni = 0; ni < 8; ++ni)
                acc[mi][ni] = __builtin_amdgcn_mfma_f32_16x16x32_bf16(
                    af[mi], bf[ni], acc[mi][ni], 0, 0, 0);
        __syncthreads();
    }

    const int orow = m0 + wm * 64;
    const int ocol = wn * 128;
#pragma unroll
    for (int mi = 0; mi < 4; ++mi) {
#pragma unroll
        for (int r = 0; r < 4; ++r) {
            int row = orow + mi * 16 + kg * 4 + r;
            if (row >= M) continue;
            float d = dis[row];
#pragma unroll
            for (int ni = 0; ni < 8; ++ni) {
                int col = ocol + ni * 16 + lr;
                out[(size_t)row * 256 + col] =
                    (u16)f2bf(d * (acc[mi][ni][r] + bias[col]));
            }
        }
    }
}

// ----------------------------------------------------------- CSR aggregation
// Wave per dst; half-wave (32 lanes) covers the 512B row with 16B/lane loads;
// wave processes 2 edges per step, main loop holds 4 edges (64B/lane) in
// flight. One 8-shuffle cross-half combine per dst.

static __device__ __forceinline__ void addv(uint4 v, float* a) {
    a[0] += bflo(v.x); a[1] += bfhi(v.x);
    a[2] += bflo(v.y); a[3] += bfhi(v.y);
    a[4] += bflo(v.z); a[5] += bfhi(v.z);
    a[6] += bflo(v.w); a[7] += bfhi(v.w);
}

static __device__ __forceinline__ void gather_row8(
    const int* __restrict__ srcl, int s, int e, int half,
    const u16* __restrict__ base, float* a) {
    int k = s;
    for (; k + 8 <= e; k += 8) {
        int s0 = __builtin_nontemporal_load(&srcl[k + half]);
        int s1 = __builtin_nontemporal_load(&srcl[k + 2 + half]);
        int s2 = __builtin_nontemporal_load(&srcl[k + 4 + half]);
        int s3 = __builtin_nontemporal_load(&srcl[k + 6 + half]);
        uint4 v0 = *(const uint4*)(base + (size_t)s0 * 256);
        uint4 v1 = *(const uint4*)(base + (size_t)s1 * 256);
        uint4 v2 = *(const uint4*)(base + (size_t)s2 * 256);
        uint4 v3 = *(const uint4*)(base + (size_t)s3 * 256);
        addv(v0, a); addv(v1, a); addv(v2, a); addv(v3, a);
    }
    for (; k + 2 <= e; k += 2) {
        int s0 = __builtin_nontemporal_load(&srcl[k + half]);
        addv(*(const uint4*)(base + (size_t)s0 * 256), a);
    }
    if (k < e && half == 0) {
        int s0 = __builtin_nontemporal_load(&srcl[k]);
        addv(*(const uint4*)(base + (size_t)s0 * 256), a);
    }
}

__global__ __launch_bounds__(256) void k_agg(
    const int* __restrict__ rowptr, const int* __restrict__ rowend,
    const int* __restrict__ srcl, const u16* __restrict__ hs,
    const float* __restrict__ dis, u16* __restrict__ out) {
    int wave = threadIdx.x >> 6;
    int lane = threadIdx.x & 63;
    int half = lane >> 5;
    int ch8 = (lane & 31) << 3;
    int dst = blockIdx.x * 4 + wave;
    if (dst >= N_NODES) return;
    int s = rowptr[dst], e = rowend[dst];
    const u16* base = hs + ch8;
    float a[8] = {0.f, 0.f, 0.f, 0.f, 0.f, 0.f, 0.f, 0.f};
    gather_row8(srcl, s, e, half, base, a);
#pragma unroll
    for (int j = 0; j < 8; ++j) a[j] += __shfl_xor(a[j], 32, 64);
    if (half == 0) {
        float d = dis[dst];
        uint4 p;
        p.x = f2bf(fmaxf(a[0] * d, 0.f)) | (f2bf(fmaxf(a[1] * d, 0.f)) << 16);
        p.y = f2bf(fmaxf(a[2] * d, 0.f)) | (f2bf(fmaxf(a[3] * d, 0.f)) << 16);
        p.z = f2bf(fmaxf(a[4] * d, 0.f)) | (f2bf(fmaxf(a[5] * d, 0.f)) << 16);
        p.w = f2bf(fmaxf(a[6] * d, 0.f)) | (f2bf(fmaxf(a[7] * d, 0.f)) << 16);
        *(uint4*)&out[(size_t)dst * 256 + ch8] = p;
    }
}

// agg2 + global max pool fused (g pre-zeroed; relu folded since max >= 0)

__global__ __launch_bounds__(256) void k_agg_pool(
    const int* __restrict__ rowptr, const int* __restrict__ rowend,
    const int* __restrict__ srcl, const u16* __restrict__ hs,
    const float* __restrict__ dis, float* __restrict__ g) {
    int wave = threadIdx.x >> 6;
    int lane = threadIdx.x & 63;
    int half = lane >> 5;
    int ch8 = (lane & 31) << 3;
    const u16* base = hs + ch8;
    float m[8] = {0.f, 0.f, 0.f, 0.f, 0.f, 0.f, 0.f, 0.f};
    for (int dst = blockIdx.x * 4 + wave; dst < N_NODES;
         dst += POOL_BLOCKS * 4) {
        int s = rowptr[dst], e = rowend[dst];
        float a[8] = {0.f, 0.f, 0.f, 0.f, 0.f, 0.f, 0.f, 0.f};
        gather_row8(srcl, s, e, half, base, a);
        float d = dis[dst];
#pragma unroll
        for (int j = 0; j < 8; ++j) {
            float v = (a[j] + __shfl_xor(a[j], 32, 64)) * d;
            m[j] = fmaxf(m[j], v);
        }
    }
    __shared__ float lm[4][256];
    if (half == 0) {
#pragma unroll
        for (int j = 0; j < 8; ++j) lm[wave][ch8 + j] = m[j];
    }
    __syncthreads();
    int t = threadIdx.x;
    float v = fmaxf(fmaxf(lm[0][t], lm[1][t]), fmaxf(lm[2][t], lm[3][t]));
    atomicMax((int*)&g[t], __float_as_int(v));
}

// --------------------------------------------------------------------- head

__global__ __launch_bounds__(128) void k_head(
    const float* __restrict__ g, const float* __restrict__ Wp,
    const float* __restrict__ bp, const float* __restrict__ Wq,
    const float* __restrict__ bq, float* __restrict__ out) {
    __shared__ float sg[NHID];
    __shared__ float red[128];
    int t = threadIdx.x;
    sg[t] = g[t];
    sg[t + 128] = g[t + 128];
    __syncthreads();

    float v = 0.0f;
    if (t < NRES_P1) {
        float acc = bp[t];
        for (int k = 0; k < NHID; ++k) acc = fmaf(sg[k], Wp[k * NRES_P1 + t], acc);
        out[t] = acc;
        v = acc;
    }
    red[t] = (t < NRES_P1) ? v : -1e30f;
    __syncthreads();
#pragma unroll
    for (int off = 64; off > 0; off >>= 1) {
        if (t < off) red[t] = fmaxf(red[t], red[t + off]);
        __syncthreads();
    }
    float mx = red[0];
    __syncthreads();
    float ex = (t < NRES_P1) ? expf(v - mx) : 0.0f;
    red[t] = ex;
    __syncthreads();
#pragma unroll
    for (int off = 64; off > 0; off >>= 1) {
        if (t < off) red[t] += red[t + off];
        __syncthreads();
    }
    float sum = red[0];
    if (t < NRES_P1) out[NRES_P1 + t] = ex / sum;

    if (t < 64) {
        float a = fmaf(sg[t], Wq[t], 0.f);
        a = fmaf(sg[t + 64],  Wq[t + 64],  a);
        a = fmaf(sg[t + 128], Wq[t + 128], a);
        a = fmaf(sg[t + 192], Wq[t + 192], a);
#pragma unroll
        for (int off = 32; off > 0; off >>= 1) a += __shfl_down(a, off, 64);
        if (t == 0) out[2 * NRES_P1] = a + bq[0];
    }
}

// -------------------------------------------------------------------- launch

static inline size_t align256(size_t x) { return (x + 255) & ~size_t(255); }

extern "C" void kernel_launch(void* const* d_in, const int* in_sizes, int n_in,
                              void* d_out, int out_size, void* d_ws,
                              size_t ws_size, hipStream_t stream) {
    (void)in_sizes; (void)n_in; (void)out_size; (void)ws_size;
    const float* x    = (const float*)d_in[0];
    const float* feat = (const float*)d_in[1];
    const int*   ei   = (const int*)d_in[2];   // int32 (harness-converted)
    const float* W1   = (const float*)d_in[3];
    const float* b1   = (const float*)d_in[4];
    const float* W2   = (const float*)d_in[5];
    const float* b2   = (const float*)d_in[6];
    const float* Wp   = (const float*)d_in[7];
    const float* bp   = (const float*)d_in[8];
    const float* Wq   = (const float*)d_in[9];
    const float* bq   = (const float*)d_in[10];
    float* out = (float*)d_out;

    char* ws = (char*)d_ws;
    size_t off = 0;
    auto alloc = [&](size_t bytes) {
        void* p = ws + off;
        off = align256(off + bytes);
        return p;
    };
    int*   deg    = (int*)alloc(4ull * N_NODES);
    int*   indeg  = (int*)alloc(4ull * N_NODES);
    int*   rowptr = (int*)alloc(4ull * (N_NODES + 1));
    int*   cursor = (int*)alloc(4ull * (N_NODES + 1));
    int*   srcl   = (int*)alloc(4ull * (N_EDGES + N_NODES));
    int*   bsum   = (int*)alloc(4ull * NB_SCAN);
    int*   bpre   = (int*)alloc(4ull * NB_SCAN);
    float* dis    = (float*)alloc(4ull * N_NODES);
    float* g      = (float*)alloc(4ull * NHID);
    u16*   W1T    = (u16*)alloc(2ull * 256 * 256);
    u16*   W2T    = (u16*)alloc(2ull * 256 * 256);
    u16*   buf1   = (u16*)alloc(2ull * N_NODES * 256);   // h1
    u16*   buf2   = (u16*)alloc(2ull * N_NODES * 256);   // h2
    u16*   buf3   = (u16*)alloc(2ull * N_NODES * 256);   // h3

    hipMemsetAsync(deg,   0, 4ull * N_NODES, stream);
    hipMemsetAsync(indeg, 0, 4ull * N_NODES, stream);
    hipMemsetAsync(g,     0, 4ull * NHID,    stream);

    k_prep_w2<<<64, 256, 0, stream>>>(W1, W2, W1T, W2T);
    k_count<<<(N_EDGES / 4 + 255) / 256, 256, 0, stream>>>(ei, deg, indeg);
    k_scan1<<<NB_SCAN, 256, 0, stream>>>(indeg, bsum);
    k_scan2<<<1, 256, 0, stream>>>(bsum, bpre);
    k_scan3<<<NB_SCAN, 256, 0, stream>>>(indeg, bpre, deg, rowptr, cursor, dis);
    k_fill<<<(N_EDGES / 4 + N_NODES / 4 + 255) / 256, 256, 0, stream>>>(
        ei, cursor, srcl);

    const int gblocks = (N_NODES + 127) / 128;
    // conv1 linear (A = concat(x,feat) f32, converted in staging)
    k_gemm_mfma<true><<<gblocks, 256, 0, stream>>>(x, feat, W1T, b1, dis,
                                                   buf1, N_NODES);
    // agg1: h2 = bf16(relu(dis .* gather-sum(h1)))
    k_agg<<<(N_NODES + 3) / 4, 256, 0, stream>>>(rowptr, cursor, srcl,
                                                 buf1, dis, buf2);
    // conv2 linear
    k_gemm_mfma<false><<<gblocks, 256, 0, stream>>>(buf2, nullptr, W2T, b2,
                                                    dis, buf3, N_NODES);
    // agg2 + fused global max pool -> g
    k_agg_pool<<<POOL_BLOCKS, 256, 0, stream>>>(rowptr, cursor, srcl,
                                                buf3, dis, g);

    k_head<<<1, 128, 0, stream>>>(g, Wp, bp, Wq, bq, out);
}

// Round 7
// 332.302 us; speedup vs baseline: 2.5946x; 1.0433x over previous
//
#include <hip/hip_runtime.h>

#define N_NODES 50000
#define N_EDGES 800000
#define NHID    256
#define NRES_P1 101

#define NB_SCAN     196        // ceil(50000/256)
#define POOL_BLOCKS 2048       // fused agg2+pool grid
#define LDK         40         // LDS k-stride (u16): 80B, 16B-aligned, 2-way banks

typedef unsigned short u16;
typedef __attribute__((ext_vector_type(8))) short short8;   // 8 bf16
typedef __attribute__((ext_vector_type(4))) float f32x4;

static __device__ __forceinline__ unsigned f2bf(float f) {  // RNE -> low 16
    unsigned u = __float_as_uint(f);
    return (u + 0x7FFF + ((u >> 16) & 1)) >> 16;
}
static __device__ __forceinline__ float bflo(unsigned p) {
    return __uint_as_float(p << 16);
}
static __device__ __forceinline__ float bfhi(unsigned p) {
    return __uint_as_float(p & 0xffff0000u);
}

// ---------------------------------------------------------------- graph prep

__global__ void k_count(const int* __restrict__ ei,
                        int* __restrict__ deg, int* __restrict__ indeg) {
    int tid = blockIdx.x * 256 + threadIdx.x;
    if (tid >= N_EDGES / 4) return;
    int4 r = *(const int4*)&ei[tid * 4];
    int4 c = *(const int4*)&ei[N_EDGES + tid * 4];
    atomicAdd(&deg[r.x], 1); atomicAdd(&deg[r.y], 1);
    atomicAdd(&deg[r.z], 1); atomicAdd(&deg[r.w], 1);
    atomicAdd(&indeg[c.x], 1); atomicAdd(&indeg[c.y], 1);
    atomicAdd(&indeg[c.z], 1); atomicAdd(&indeg[c.w], 1);
}

// 3-kernel exclusive scan of (indeg+1) -> rowptr (+cursor); dis fused in scan3

__global__ __launch_bounds__(256) void k_scan1(const int* __restrict__ cnt,
                                               int* __restrict__ bsum) {
    int t = threadIdx.x, lane = t & 63, wid = t >> 6;
    int i = blockIdx.x * 256 + t;
    int v = (i < N_NODES) ? cnt[i] + 1 : 0;      // +1 = self-loop
#pragma unroll
    for (int off = 32; off > 0; off >>= 1) v += __shfl_down(v, off, 64);
    __shared__ int ws[4];
    if (lane == 0) ws[wid] = v;
    __syncthreads();
    if (t == 0) bsum[blockIdx.x] = ws[0] + ws[1] + ws[2] + ws[3];
}

__global__ __launch_bounds__(256) void k_scan2(const int* __restrict__ bsum,
                                               int* __restrict__ bpre) {
    __shared__ int s[256];
    int t = threadIdx.x;
    int v0 = (t < NB_SCAN) ? bsum[t] : 0;
    s[t] = v0;
    __syncthreads();
    for (int off = 1; off < 256; off <<= 1) {
        int v = (t >= off) ? s[t - off] : 0;
        __syncthreads();
        s[t] += v;
        __syncthreads();
    }
    if (t < NB_SCAN) bpre[t] = s[t] - v0;   // exclusive
}

__global__ __launch_bounds__(256) void k_scan3(
    const int* __restrict__ cnt, const int* __restrict__ bpre,
    const int* __restrict__ deg, int* __restrict__ rowptr,
    int* __restrict__ cursor, float* __restrict__ dis) {
    int t = threadIdx.x, lane = t & 63, wid = t >> 6;
    int i = blockIdx.x * 256 + t;
    int v = (i < N_NODES) ? cnt[i] + 1 : 0;
    int sc = v;
#pragma unroll
    for (int off = 1; off < 64; off <<= 1) {
        int y = __shfl_up(sc, off, 64);
        if (lane >= off) sc += y;
    }
    __shared__ int wsum[4], wexcl[4];
    if (lane == 63) wsum[wid] = sc;
    __syncthreads();
    if (t == 0) {
        int r = 0;
#pragma unroll
        for (int w = 0; w < 4; ++w) { wexcl[w] = r; r += wsum[w]; }
    }
    __syncthreads();
    if (i < N_NODES) {
        int excl = bpre[blockIdx.x] + wexcl[wid] + sc - v;
        rowptr[i] = excl;
        cursor[i] = excl;
        dis[i] = rsqrtf((float)(deg[i] + 1));
    }
}

__global__ void k_fill(const int* __restrict__ ei,
                       int* __restrict__ cursor, int* __restrict__ srcl) {
    int tid = blockIdx.x * 256 + threadIdx.x;
    if (tid < N_EDGES / 4) {
        int4 r = *(const int4*)&ei[tid * 4];
        int4 c = *(const int4*)&ei[N_EDGES + tid * 4];
        int p;
        p = atomicAdd(&cursor[c.x], 1); srcl[p] = r.x;
        p = atomicAdd(&cursor[c.y], 1); srcl[p] = r.y;
        p = atomicAdd(&cursor[c.z], 1); srcl[p] = r.z;
        p = atomicAdd(&cursor[c.w], 1); srcl[p] = r.w;
    } else if (tid < N_EDGES / 4 + N_NODES / 4) {
        int n4 = (tid - N_EDGES / 4) * 4;
#pragma unroll
        for (int j = 0; j < 4; ++j) {
            int n = n4 + j;
            int p = atomicAdd(&cursor[n], 1);
            srcl[p] = n;                        // self loop
        }
    }
}

// both weight transposes in one dispatch: WT[n][k] = bf16(W[k][n])
__global__ void k_prep_w2(const float* __restrict__ W1, const float* __restrict__ W2,
                          u16* __restrict__ W1T, u16* __restrict__ W2T) {
    int tid = blockIdx.x * 256 + threadIdx.x;    // 16384
    const float* W = (tid < 8192) ? W1 : W2;
    u16* WT = (tid < 8192) ? W1T : W2T;
    int id = tid & 8191;
    int n = id >> 5, k8 = (id & 31) << 3;
    u16 tmp[8];
#pragma unroll
    for (int i = 0; i < 8; ++i) tmp[i] = (u16)f2bf(W[(size_t)(k8 + i) * 256 + n]);
    *(uint4*)&WT[(size_t)n * 256 + k8] = *(uint4*)tmp;
}

// ------------------------------------------------------------- MFMA GEMM
// out[m][n] = bf16( dis[m] * ( sum_k A[m][k] * W[k][n] + bias[n] ) )
// BM=128, BN=256 (full N, single pass over A), BK=32, 256 thr = 2x2 waves,
// wave-tile 64x128 (acc 4x8 frags). SPLIT: A = concat(x,feat) f32, converted
// to bf16 during staging (fused cvtA).

template <bool SPLIT>
__global__ __launch_bounds__(256, 2) void k_gemm_mfma(
    const void* __restrict__ A0v, const float* __restrict__ A1,
    const u16* __restrict__ WT, const float* __restrict__ bias,
    const float* __restrict__ dis, u16* __restrict__ out, int M) {
    __shared__ u16 As[128][LDK];
    __shared__ u16 Bs[256][LDK];
    const int t = threadIdx.x;
    const int m0 = blockIdx.x * 128;
    const int lane = t & 63, wave = t >> 6;
    const int wm = wave & 1, wn = wave >> 1;
    const int lr = lane & 15, kg = lane >> 4;

    f32x4 acc[4][8] = {};

    for (int k0 = 0; k0 < 256; k0 += 32) {
        // A tile: 128 rows x 32 k = 512 chunks of 8 bf16; 2 per thread
#pragma unroll
        for (int i = 0; i < 2; ++i) {
            int idx = i * 256 + t;
            int row = idx >> 2, kc = (idx & 3) << 3;
            int grow = m0 + row;
            uint4 pk = {0u, 0u, 0u, 0u};
            if (grow < M) {
                if (SPLIT) {
                    int k = k0 + kc;            // 8-aligned, never straddles 128
                    const float* src = (k < 128)
                        ? ((const float*)A0v + (size_t)grow * 128 + k)
                        : (A1 + (size_t)grow * 128 + (k - 128));
                    float4 f0 = *(const float4*)src;
                    float4 f1 = *(const float4*)(src + 4);
                    pk.x = f2bf(f0.x) | (f2bf(f0.y) << 16);
                    pk.y = f2bf(f0.z) | (f2bf(f0.w) << 16);
                    pk.z = f2bf(f1.x) | (f2bf(f1.y) << 16);
                    pk.w = f2bf(f1.z) | (f2bf(f1.w) << 16);
                } else {
                    pk = *(const uint4*)((const u16*)A0v +
                                         (size_t)grow * 256 + k0 + kc);
                }
            }
            *(uint4*)&As[row][kc] = pk;
        }
        // B tile: 256 n-rows x 32 k = 1024 chunks; 4 per thread
#pragma unroll
        for (int i = 0; i < 4; ++i) {
            int idx = i * 256 + t;
            int n = idx >> 2, kc = (idx & 3) << 3;
            *(uint4*)&Bs[n][kc] = *(const uint4*)&WT[(size_t)n * 256 + k0 + kc];
        }
        __syncthreads();
        short8 af[4], bf[8];
#pragma unroll
        for (int mi = 0; mi < 4; ++mi)
            af[mi] = *(const short8*)&As[wm * 64 + mi * 16 + lr][kg * 8];
#pragma unroll
        for (int ni = 0; ni < 8; ++ni)
            bf[ni] = *(const short8*)&Bs[wn * 128 + ni * 16 + lr][kg * 8];
#pragma unroll
        for (int mi = 0; mi < 4; ++mi)
#pragma unroll
            for (int ni = 0; ni < 8; ++ni)
                acc[mi][ni] = __builtin_amdgcn_mfma_f32_16x16x32_bf16(
                    af[mi], bf[ni], acc[mi][ni], 0, 0, 0);
        __syncthreads();
    }

    const int orow = m0 + wm * 64;
    const int ocol = wn * 128;
#pragma unroll
    for (int mi = 0; mi < 4; ++mi) {
#pragma unroll
        for (int r = 0; r < 4; ++r) {
            int row = orow + mi * 16 + kg * 4 + r;
            if (row >= M) continue;
            float d = dis[row];
#pragma unroll
            for (int ni = 0; ni < 8; ++ni) {
                int col = ocol + ni * 16 + lr;
                out[(size_t)row * 256 + col] =
                    (u16)f2bf(d * (acc[mi][ni][r] + bias[col]));
            }
        }
    }
}

// ----------------------------------------------------------- CSR aggregation
// Wave per dst. Per 64-edge chunk: ONE coalesced srcl load -> LDS; edge loop
// reads indices from LDS via broadcast b128 (off the critical path) and keeps
// 16 edges in flight per wave (half-wave owns 8 contiguous edges x uint4).

static __device__ __forceinline__ void addv4(uint4 v, float* a) {
    a[0] += bflo(v.x); a[1] += bfhi(v.x);
    a[2] += bflo(v.y); a[3] += bfhi(v.y);
    a[4] += bflo(v.z); a[5] += bfhi(v.z);
    a[6] += bflo(v.w); a[7] += bfhi(v.w);
}

// idxb: this wave's 64-entry LDS index buffer; nn = edges in chunk
static __device__ __forceinline__ void gather_chunk(
    const int* __restrict__ idxb, int nn, int half,
    const u16* __restrict__ base, float* a) {
    int j = 0;
    for (; j + 16 <= nn; j += 16) {
        const int* p = idxb + j + half * 8;
        int4 q0 = *(const int4*)p;          // ds_read_b128 broadcast
        int4 q1 = *(const int4*)(p + 4);
        uint4 v0 = *(const uint4*)(base + (size_t)q0.x * 256);
        uint4 v1 = *(const uint4*)(base + (size_t)q0.y * 256);
        uint4 v2 = *(const uint4*)(base + (size_t)q0.z * 256);
        uint4 v3 = *(const uint4*)(base + (size_t)q0.w * 256);
        uint4 v4 = *(const uint4*)(base + (size_t)q1.x * 256);
        uint4 v5 = *(const uint4*)(base + (size_t)q1.y * 256);
        uint4 v6 = *(const uint4*)(base + (size_t)q1.z * 256);
        uint4 v7 = *(const uint4*)(base + (size_t)q1.w * 256);
        addv4(v0, a); addv4(v1, a); addv4(v2, a); addv4(v3, a);
        addv4(v4, a); addv4(v5, a); addv4(v6, a); addv4(v7, a);
    }
    for (; j + 2 <= nn; j += 2) {           // pairs: half h takes edge j+h
        int s0 = idxb[j + half];
        addv4(*(const uint4*)(base + (size_t)s0 * 256), a);
    }
    if (j < nn && half == 0) {              // masked single
        int s0 = idxb[j];
        addv4(*(const uint4*)(base + (size_t)s0 * 256), a);
    }
}

__global__ __launch_bounds__(256) void k_agg(
    const int* __restrict__ rowptr, const int* __restrict__ rowend,
    const int* __restrict__ srcl, const u16* __restrict__ hs,
    const float* __restrict__ dis, u16* __restrict__ out) {
    __shared__ int idxb[4][64];
    int wave = threadIdx.x >> 6;
    int lane = threadIdx.x & 63;
    int half = lane >> 5;
    int ch8 = (lane & 31) << 3;
    int dst = blockIdx.x * 4 + wave;
    if (dst >= N_NODES) return;
    int s = rowptr[dst], e = rowend[dst];
    const u16* base = hs + ch8;
    float a[8] = {0.f, 0.f, 0.f, 0.f, 0.f, 0.f, 0.f, 0.f};
    for (int k0 = s; k0 < e; k0 += 64) {
        int nn = min(64, e - k0);
        idxb[wave][lane] = srcl[k0 + (lane < nn ? lane : nn - 1)];
        gather_chunk(&idxb[wave][0], nn, half, base, a);
    }
#pragma unroll
    for (int j = 0; j < 8; ++j) a[j] += __shfl_xor(a[j], 32, 64);
    if (half == 0) {
        float d = dis[dst];
        uint4 p;
        p.x = f2bf(fmaxf(a[0] * d, 0.f)) | (f2bf(fmaxf(a[1] * d, 0.f)) << 16);
        p.y = f2bf(fmaxf(a[2] * d, 0.f)) | (f2bf(fmaxf(a[3] * d, 0.f)) << 16);
        p.z = f2bf(fmaxf(a[4] * d, 0.f)) | (f2bf(fmaxf(a[5] * d, 0.f)) << 16);
        p.w = f2bf(fmaxf(a[6] * d, 0.f)) | (f2bf(fmaxf(a[7] * d, 0.f)) << 16);
        *(uint4*)&out[(size_t)dst * 256 + ch8] = p;
    }
}

// agg2 + global max pool fused (g pre-zeroed; relu folded since max >= 0)

__global__ __launch_bounds__(256) void k_agg_pool(
    const int* __restrict__ rowptr, const int* __restrict__ rowend,
    const int* __restrict__ srcl, const u16* __restrict__ hs,
    const float* __restrict__ dis, float* __restrict__ g) {
    __shared__ int idxb[4][64];
    int wave = threadIdx.x >> 6;
    int lane = threadIdx.x & 63;
    int half = lane >> 5;
    int ch8 = (lane & 31) << 3;
    const u16* base = hs + ch8;
    float m[8] = {0.f, 0.f, 0.f, 0.f, 0.f, 0.f, 0.f, 0.f};
    for (int dst = blockIdx.x * 4 + wave; dst < N_NODES;
         dst += POOL_BLOCKS * 4) {
        int s = rowptr[dst], e = rowend[dst];
        float a[8] = {0.f, 0.f, 0.f, 0.f, 0.f, 0.f, 0.f, 0.f};
        for (int k0 = s; k0 < e; k0 += 64) {
            int nn = min(64, e - k0);
            idxb[wave][lane] = srcl[k0 + (lane < nn ? lane : nn - 1)];
            gather_chunk(&idxb[wave][0], nn, half, base, a);
        }
        float d = dis[dst];
#pragma unroll
        for (int j = 0; j < 8; ++j) {
            float v = (a[j] + __shfl_xor(a[j], 32, 64)) * d;
            m[j] = fmaxf(m[j], v);
        }
    }
    __shared__ float lm[4][256];
    if (half == 0) {
#pragma unroll
        for (int j = 0; j < 4; ++j) lm[wave][ch8 + j] = m[j];
#pragma unroll
        for (int j = 4; j < 8; ++j) lm[wave][ch8 + j] = m[j];
    }
    __syncthreads();
    int t = threadIdx.x;
    float v = fmaxf(fmaxf(lm[0][t], lm[1][t]), fmaxf(lm[2][t], lm[3][t]));
    atomicMax((int*)&g[t], __float_as_int(v));
}

// --------------------------------------------------------------------- head

__global__ __launch_bounds__(128) void k_head(
    const float* __restrict__ g, const float* __restrict__ Wp,
    const float* __restrict__ bp, const float* __restrict__ Wq,
    const float* __restrict__ bq, float* __restrict__ out) {
    __shared__ float sg[NHID];
    __shared__ float red[128];
    int t = threadIdx.x;
    sg[t] = g[t];
    sg[t + 128] = g[t + 128];
    __syncthreads();

    float v = 0.0f;
    if (t < NRES_P1) {
        float acc = bp[t];
        for (int k = 0; k < NHID; ++k) acc = fmaf(sg[k], Wp[k * NRES_P1 + t], acc);
        out[t] = acc;
        v = acc;
    }
    red[t] = (t < NRES_P1) ? v : -1e30f;
    __syncthreads();
#pragma unroll
    for (int off = 64; off > 0; off >>= 1) {
        if (t < off) red[t] = fmaxf(red[t], red[t + off]);
        __syncthreads();
    }
    float mx = red[0];
    __syncthreads();
    float ex = (t < NRES_P1) ? expf(v - mx) : 0.0f;
    red[t] = ex;
    __syncthreads();
#pragma unroll
    for (int off = 64; off > 0; off >>= 1) {
        if (t < off) red[t] += red[t + off];
        __syncthreads();
    }
    float sum = red[0];
    if (t < NRES_P1) out[NRES_P1 + t] = ex / sum;

    if (t < 64) {
        float a = fmaf(sg[t], Wq[t], 0.f);
        a = fmaf(sg[t + 64],  Wq[t + 64],  a);
        a = fmaf(sg[t + 128], Wq[t + 128], a);
        a = fmaf(sg[t + 192], Wq[t + 192], a);
#pragma unroll
        for (int off = 32; off > 0; off >>= 1) a += __shfl_down(a, off, 64);
        if (t == 0) out[2 * NRES_P1] = a + bq[0];
    }
}

// -------------------------------------------------------------------- launch

static inline size_t align256(size_t x) { return (x + 255) & ~size_t(255); }

extern "C" void kernel_launch(void* const* d_in, const int* in_sizes, int n_in,
                              void* d_out, int out_size, void* d_ws,
                              size_t ws_size, hipStream_t stream) {
    (void)in_sizes; (void)n_in; (void)out_size; (void)ws_size;
    const float* x    = (const float*)d_in[0];
    const float* feat = (const float*)d_in[1];
    const int*   ei   = (const int*)d_in[2];   // int32 (harness-converted)
    const float* W1   = (const float*)d_in[3];
    const float* b1   = (const float*)d_in[4];
    const float* W2   = (const float*)d_in[5];
    const float* b2   = (const float*)d_in[6];
    const float* Wp   = (const float*)d_in[7];
    const float* bp   = (const float*)d_in[8];
    const float* Wq   = (const float*)d_in[9];
    const float* bq   = (const float*)d_in[10];
    float* out = (float*)d_out;

    char* ws = (char*)d_ws;
    size_t off = 0;
    auto alloc = [&](size_t bytes) {
        void* p = ws + off;
        off = align256(off + bytes);
        return p;
    };
    int*   deg    = (int*)alloc(4ull * N_NODES);
    int*   indeg  = (int*)alloc(4ull * N_NODES);
    int*   rowptr = (int*)alloc(4ull * (N_NODES + 1));
    int*   cursor = (int*)alloc(4ull * (N_NODES + 1));
    int*   srcl   = (int*)alloc(4ull * (N_EDGES + N_NODES));
    int*   bsum   = (int*)alloc(4ull * NB_SCAN);
    int*   bpre   = (int*)alloc(4ull * NB_SCAN);
    float* dis    = (float*)alloc(4ull * N_NODES);
    float* g      = (float*)alloc(4ull * NHID);
    u16*   W1T    = (u16*)alloc(2ull * 256 * 256);
    u16*   W2T    = (u16*)alloc(2ull * 256 * 256);
    u16*   buf1   = (u16*)alloc(2ull * N_NODES * 256);   // h1
    u16*   buf2   = (u16*)alloc(2ull * N_NODES * 256);   // h2
    u16*   buf3   = (u16*)alloc(2ull * N_NODES * 256);   // h3

    hipMemsetAsync(deg,   0, 4ull * N_NODES, stream);
    hipMemsetAsync(indeg, 0, 4ull * N_NODES, stream);
    hipMemsetAsync(g,     0, 4ull * NHID,    stream);

    k_prep_w2<<<64, 256, 0, stream>>>(W1, W2, W1T, W2T);
    k_count<<<(N_EDGES / 4 + 255) / 256, 256, 0, stream>>>(ei, deg, indeg);
    k_scan1<<<NB_SCAN, 256, 0, stream>>>(indeg, bsum);
    k_scan2<<<1, 256, 0, stream>>>(bsum, bpre);
    k_scan3<<<NB_SCAN, 256, 0, stream>>>(indeg, bpre, deg, rowptr, cursor, dis);
    k_fill<<<(N_EDGES / 4 + N_NODES / 4 + 255) / 256, 256, 0, stream>>>(
        ei, cursor, srcl);

    const int gblocks = (N_NODES + 127) / 128;
    // conv1 linear (A = concat(x,feat) f32, converted in staging)
    k_gemm_mfma<true><<<gblocks, 256, 0, stream>>>(x, feat, W1T, b1, dis,
                                                   buf1, N_NODES);
    // agg1: h2 = bf16(relu(dis .* gather-sum(h1)))
    k_agg<<<(N_NODES + 3) / 4, 256, 0, stream>>>(rowptr, cursor, srcl,
                                                 buf1, dis, buf2);
    // conv2 linear
    k_gemm_mfma<false><<<gblocks, 256, 0, stream>>>(buf2, nullptr, W2T, b2,
                                                    dis, buf3, N_NODES);
    // agg2 + fused global max pool -> g
    k_agg_pool<<<POOL_BLOCKS, 256, 0, stream>>>(rowptr, cursor, srcl,
                                                buf3, dis, g);

    k_head<<<1, 128, 0, stream>>>(g, Wp, bp, Wq, bq, out);
}